// Round 3
// baseline (441.053 us; speedup 1.0000x reference)
//
#include <hip/hip_runtime.h>
#include <stdint.h>

// Koopman autoencoder — round 3 restructure (MI355X / gfx950).
// Weights in REGISTERS (col-sliced per wave, double-buffered), h in LDS dbuf,
// 1 barrier/layer, proj1@proj2 fused into Wcomb, full-line NT output stores
// via swizzled LDS transpose buffer. f16 MFMA 16x16x32, fp32 accum.

typedef _Float16 h8 __attribute__((ext_vector_type(8)));
typedef _Float16 h4 __attribute__((ext_vector_type(4)));
typedef float    f4 __attribute__((ext_vector_type(4)));

#define ROWS_AUTO 104448   // 2048*51

// half-element offsets inside wt region of ws (all mats stored as W^T [n][k])
#define WT_ENCW      0
#define WT_ENCWOUT   (4*16384)
#define WT_DECW      (5*16384)
#define WT_DECWOUT   (9*16384)
#define WT_WENCI     (10*16384)            // [32][128] (zero-padded rows 21..31)
#define WT_COMB      (10*16384 + 4096)     // (WencI@WdecI)^T [128][128]

// ws byte offsets
#define MS_OFF_B    0x60000    // Ms^T f16 [50][128][32]
#define ACH_OFF_B   0xC8000    // 50*441 floats (L^{s+1} chain)
#define FET0_OFF_B  0xE0000    // f16 [2048][32] full_enc at t=0

// LDS: h dbuf 2x16KB [0,32K) (aliased by f32 transpose buf at epilogues),
//      pe slot [32K,48K), biases [48K, 48K+5K)
#define LDS_BYTES 54272
#define B_ENCB   0
#define B_DECB   512
#define B_ENCBO  1024
#define B_DECBO  1152

__device__ __forceinline__ f4 mfma16(h8 a, h8 b, f4 c) {
  return __builtin_amdgcn_mfma_f32_16x16x32_f16(a, b, c, 0, 0, 0);
}
// h buffer: row stride 256B, 16B chunks XOR-swizzled by row (bank fix)
__device__ __forceinline__ int hoff(int buf, int rl, int c) {
  return buf*16384 + rl*256 + (((c) ^ (rl & 7)) << 4);
}
__device__ __forceinline__ int peoff(int rl, int c) {
  return 32768 + rl*256 + (((c) ^ (rl & 7)) << 4);
}
__device__ __forceinline__ h8 cvt8(f4 a, f4 b) {
  h8 r;
  r[0]=(_Float16)a[0]; r[1]=(_Float16)a[1]; r[2]=(_Float16)a[2]; r[3]=(_Float16)a[3];
  r[4]=(_Float16)b[0]; r[5]=(_Float16)b[1]; r[6]=(_Float16)b[2]; r[7]=(_Float16)b[3];
  return r;
}

// wave's 32-col slice of a 128x128 W^T: B[nt*4+ks], coalesced 64B segments
__device__ __forceinline__ void loadW(h8 B[8], const _Float16* gW, int nbase, int r15, int hi) {
#pragma unroll
  for (int nt = 0; nt < 2; ++nt)
#pragma unroll
    for (int ks = 0; ks < 4; ++ks)
      B[nt*4+ks] = *(const h8*)(gW + (size_t)(nbase + nt*16 + r15)*128 + ks*32 + hi*8);
}
// K=32 slice of a [128][32] W^T
__device__ __forceinline__ void loadW32(h8 B[2], const _Float16* g, int nbase, int r15, int hi) {
  B[0] = *(const h8*)(g + (size_t)(nbase + r15)*32 + hi*8);
  B[1] = *(const h8*)(g + (size_t)(nbase + 16 + r15)*32 + hi*8);
}

// [32 rows (rg)] x [128 k] @ regs-B -> acc[2rt][2nt]
__device__ __forceinline__ void mmF(const char* sm, int cur, int rg, const h8 B[8],
                                    f4 acc[2][2], int r15, int hi) {
#pragma unroll
  for (int rt = 0; rt < 2; ++rt)
#pragma unroll
    for (int nt = 0; nt < 2; ++nt) acc[rt][nt] = (f4){0.f,0.f,0.f,0.f};
#pragma unroll
  for (int ks = 0; ks < 4; ++ks) {
    int c = ks*4 + hi;
    h8 a0 = *(const h8*)(sm + hoff(cur, rg*32 + r15, c));
    h8 a1 = *(const h8*)(sm + hoff(cur, rg*32 + 16 + r15, c));
    acc[0][0] = mfma16(a0, B[ks],   acc[0][0]);
    acc[0][1] = mfma16(a0, B[4+ks], acc[0][1]);
    acc[1][0] = mfma16(a1, B[ks],   acc[1][0]);
    acc[1][1] = mfma16(a1, B[4+ks], acc[1][1]);
  }
}
__device__ __forceinline__ void mm32(const char* sm, int cur, int rg, const h8 B[2],
                                     f4 acc[2][2], int r15, int hi) {
#pragma unroll
  for (int rt = 0; rt < 2; ++rt)
#pragma unroll
    for (int nt = 0; nt < 2; ++nt) acc[rt][nt] = (f4){0.f,0.f,0.f,0.f};
  int c = hi;
  h8 a0 = *(const h8*)(sm + hoff(cur, rg*32 + r15, c));
  h8 a1 = *(const h8*)(sm + hoff(cur, rg*32 + 16 + r15, c));
  acc[0][0] = mfma16(a0, B[0], acc[0][0]);
  acc[0][1] = mfma16(a0, B[1], acc[0][1]);
  acc[1][0] = mfma16(a1, B[0], acc[1][0]);
  acc[1][1] = mfma16(a1, B[1], acc[1][1]);
}

// bias(+relu) -> h[buf] f16 (wave's own col slice; block rows shared)
__device__ __forceinline__ void hwrite(char* sm, int buf, int rg, int wbase,
                                       const f4 acc[2][2], const float* bl, int bo,
                                       bool relu, int r15, int hi) {
#pragma unroll
  for (int nt = 0; nt < 2; ++nt) {
    int n = wbase + nt*16 + r15;
    float bv = (bo >= 0) ? bl[bo + n] : 0.f;
#pragma unroll
    for (int rt = 0; rt < 2; ++rt)
#pragma unroll
      for (int d = 0; d < 4; ++d) {
        int rl = rg*32 + rt*16 + hi*4 + d;
        float v = acc[rt][nt][d] + bv;
        if (relu) v = fmaxf(v, 0.f);
        *(_Float16*)(sm + hoff(buf, rl, n >> 3) + (n & 7)*2) = (_Float16)v;
      }
  }
}

// readback swizzled f32 trbuf rows -> full-line NT vector stores
__device__ __forceinline__ void store_rows(const char* sm, float* gbase, int rstride,
                                           int w, int lane) {
  int rr = w*8 + (lane >> 3), qb = (lane & 7)*4;
#pragma unroll
  for (int i = 0; i < 4; ++i) {
    int q = qb + i;
    f4 v = *(const f4*)(sm + rr*512 + ((q ^ ((rr & 7) << 2)) << 4));
    __builtin_nontemporal_store(v, (f4*)(gbase + (size_t)rr*rstride + q*4));
  }
}

#define TRWRITE(SKEXPR, BOUT)                                                   \
  _Pragma("unroll")                                                             \
  for (int nt = 0; nt < 2; ++nt) { int n = wbase + nt*16 + r15;                 \
    float bv = bl[(BOUT) + n];                                                  \
    _Pragma("unroll")                                                           \
    for (int rt = 0; rt < 2; ++rt)                                              \
      _Pragma("unroll")                                                         \
      for (int d = 0; d < 4; ++d) { int r = rg*32 + rt*16 + hi*4 + d;           \
        float sk = (SKEXPR);                                                    \
        float v = acc[rt][nt][d] + bv + sk;                                     \
        int q = n >> 2;                                                         \
        *(float*)(sm + r*512 + ((q ^ ((r & 7) << 2)) << 4) + (n & 3)*4) = v; } }

#define LAYER(BC, BN, NXTOFF, BO, RELU) do {                                    \
    loadW(BN, wt + (NXTOFF), wbase, r15, hi);                                   \
    mmF(sm, cur, rg, BC, acc, r15, hi);                                         \
    hwrite(sm, cur ^ 1, rg, wbase, acc, bl, BO, RELU, r15, hi);                 \
    __syncthreads(); cur ^= 1;                                                  \
  } while (0)

// ---------------- prep kernels ----------------

__global__ __launch_bounds__(512) void k_prep(
    const float* __restrict__ encW, const float* __restrict__ encWout,
    const float* __restrict__ decW, const float* __restrict__ decWout,
    const float* __restrict__ wencI, const float* __restrict__ L,
    _Float16* __restrict__ wt, float* __restrict__ ach) {
  __shared__ float chA[441], chB[441];
  int m = blockIdx.y, tid = threadIdx.x;
  if (m == 11) {                                  // serial L-power chain
    if (blockIdx.x != 0) return;
    if (tid < 441) chA[tid] = L[tid];
    __syncthreads();
    for (int s = 0; s < 50; ++s) {
      if (tid < 441) ach[s*441 + tid] = chA[tid];
      if (s == 49) break;
      if (tid < 441) {
        int i = tid / 21, j = tid % 21; float a = 0.f;
        for (int k = 0; k < 21; ++k) a += chA[i*21 + k] * L[k*21 + j];
        chB[tid] = a;
      }
      __syncthreads();
      if (tid < 441) chA[tid] = chB[tid];
      __syncthreads();
    }
    return;
  }
  int idx = blockIdx.x*512 + tid;
  if (m < 10) {
    if (idx >= 16384) return;
    const float* src; _Float16* dst;
    if (m < 4)       { src = encW + m*16384;     dst = wt + WT_ENCW + m*16384; }
    else if (m == 4) { src = encWout;            dst = wt + WT_ENCWOUT; }
    else if (m < 9)  { src = decW + (m-5)*16384; dst = wt + WT_DECW + (m-5)*16384; }
    else             { src = decWout;            dst = wt + WT_DECWOUT; }
    int n = idx >> 7, k = idx & 127;
    dst[idx] = (_Float16)src[k*128 + n];          // W^T[n][k]
  } else {                                        // W_enc_inner -> [32][128] padded
    if (idx >= 32*128) return;
    int n = idx >> 7, k = idx & 127;
    wt[WT_WENCI + idx] = (_Float16)((n < 21) ? wencI[k*21 + n] : 0.f);
  }
}

__global__ __launch_bounds__(512) void k_aux(const float* __restrict__ ach,
                                             const float* __restrict__ wencI,
                                             const float* __restrict__ wdecI,
                                             _Float16* __restrict__ mst,
                                             _Float16* __restrict__ wt) {
  __shared__ float sA[2688], sB[2688];
  int s = blockIdx.x, t = threadIdx.x;
  if (s < 50) {                                   // Ms^T [128 n][32 k]
    for (int i = t; i < 441; i += 512) sA[i] = ach[s*441 + i];
    __syncthreads();
    for (int idx = t; idx < 4096; idx += 512) {
      int n = idx >> 5, k = idx & 31;
      float a = 0.f;
      if (k < 21) for (int j = 0; j < 21; ++j) a += sA[k*21 + j] * wdecI[j*128 + n];
      mst[(size_t)s*4096 + idx] = (_Float16)a;
    }
  } else {                                        // Wcomb^T[n][k] = sum_t wencI[k][t]*wdecI[t][n]
    for (int i = t; i < 2688; i += 512) { sA[i] = wencI[i]; sB[i] = wdecI[i]; }
    __syncthreads();
    for (int idx = t; idx < 16384; idx += 512) {
      int n = idx >> 7, k = idx & 127;
      float a = 0.f;
      for (int j = 0; j < 21; ++j) a += sA[k*21 + j] * sB[j*128 + n];
      wt[WT_COMB + idx] = (_Float16)a;
    }
  }
}

// ---------------- main fused kernel (64 rows/block, 8 waves) ----------------

__global__ __launch_bounds__(512, 4) void k_fused(
    const float* __restrict__ x, const _Float16* __restrict__ wt,
    const float* __restrict__ enc_b, const float* __restrict__ enc_bout,
    const float* __restrict__ dec_b, const float* __restrict__ dec_bout,
    float* __restrict__ out1, float* __restrict__ out2, _Float16* __restrict__ fet0) {
  __shared__ char sm[LDS_BYTES];
  float* bl = (float*)(sm + 49152);
  int tid = threadIdx.x, w = tid >> 6, lane = tid & 63;
  int r15 = lane & 15, hi = lane >> 4;
  int rg = w >> 2, cg = w & 3, wbase = cg*32;
  int bid = blockIdx.x;
  h8 Ba[8], Bb[8];
  f4 acc[2][2];

  if (bid < 1632) {
    size_t rowbase = (size_t)bid * 64;
    loadW(Ba, wt + WT_ENCW, wbase, r15, hi);
#pragma unroll
    for (int i = 0; i < 2; ++i) {                 // stage x -> h[0]
      int idx = i*512 + tid, rl = idx >> 4, c = idx & 15;
      const float* s = x + (rowbase + rl)*128 + c*8;
      f4 v0 = *(const f4*)s, v1 = *(const f4*)(s + 4);
      *(h8*)(sm + hoff(0, rl, c)) = cvt8(v0, v1);
    }
    bl[tid] = enc_b[tid]; bl[512 + tid] = dec_b[tid];
    if (tid < 128) { bl[1024 + tid] = enc_bout[tid]; bl[1152 + tid] = dec_bout[tid]; }
    __syncthreads();
    int cur = 0;
    // encoder
    LAYER(Ba, Bb, WT_ENCW + 16384,   B_ENCB + 0,   true);
    LAYER(Bb, Ba, WT_ENCW + 2*16384, B_ENCB + 128, true);
    LAYER(Ba, Bb, WT_ENCW + 3*16384, B_ENCB + 256, true);
    LAYER(Bb, Ba, WT_ENCWOUT,        B_ENCB + 384, true);
    loadW(Bb, wt + WT_COMB, wbase, r15, hi);      // prefetch Wcomb
    mmF(sm, cur, rg, Ba, acc, r15, hi);           // encWout
    // pe = acc + enc_bout + x ; to h[cur^1] and pe slot
#pragma unroll
    for (int nt = 0; nt < 2; ++nt) {
      int n = wbase + nt*16 + r15; float bv = bl[B_ENCBO + n];
#pragma unroll
      for (int rt = 0; rt < 2; ++rt)
#pragma unroll
        for (int d = 0; d < 4; ++d) {
          int rl = rg*32 + rt*16 + hi*4 + d;
          float xv = x[(rowbase + rl)*128 + n];
          float v = acc[rt][nt][d] + bv + xv;
          _Float16 hv = (_Float16)v;
          *(_Float16*)(sm + hoff(cur ^ 1, rl, n >> 3) + (n & 7)*2) = hv;
          *(_Float16*)(sm + peoff(rl, n >> 3) + (n & 7)*2) = hv;
        }
    }
    __syncthreads(); cur ^= 1;
    // comb: part_dec = pe @ Wcomb (no bias/relu); keep in regs, h stays = pe
    loadW(Ba, wt + WT_DECW, wbase, r15, hi);      // prefetch dec L0
    mmF(sm, cur, rg, Bb, acc, r15, hi);
    h4 pd[2][2];
#pragma unroll
    for (int rt = 0; rt < 2; ++rt)
#pragma unroll
      for (int nt = 0; nt < 2; ++nt)
#pragma unroll
        for (int d = 0; d < 4; ++d) pd[rt][nt][d] = (_Float16)acc[rt][nt][d];
    // dec stream B (input pe in h[cur])
    LAYER(Ba, Bb, WT_DECW + 16384,   B_DECB + 0,   true);
    LAYER(Bb, Ba, WT_DECW + 2*16384, B_DECB + 128, true);
    LAYER(Ba, Bb, WT_DECW + 3*16384, B_DECB + 256, true);
    LAYER(Bb, Ba, WT_DECWOUT,        B_DECB + 384, true);
    loadW(Bb, wt + WT_DECW, wbase, r15, hi);      // prefetch dec L0 for stream A
    mmF(sm, cur, rg, Ba, acc, r15, hi);           // decWout
    __syncthreads();                              // all h reads done (trbuf aliases h)
    TRWRITE((float)*(const _Float16*)(sm + peoff(r, n >> 3) + (n & 7)*2), B_DECBO);
    __syncthreads();
    store_rows(sm, out2 + rowbase*128, 128, w, lane);
    __syncthreads();
    // restage pd -> h[0]
#pragma unroll
    for (int nt = 0; nt < 2; ++nt) {
      int n = wbase + nt*16 + r15;
#pragma unroll
      for (int rt = 0; rt < 2; ++rt)
#pragma unroll
        for (int d = 0; d < 4; ++d) {
          int rl = rg*32 + rt*16 + hi*4 + d;
          *(_Float16*)(sm + hoff(0, rl, n >> 3) + (n & 7)*2) = pd[rt][nt][d];
        }
    }
    __syncthreads();
    cur = 0;
    // dec stream A (input pd)
    LAYER(Bb, Ba, WT_DECW + 16384,   B_DECB + 0,   true);
    LAYER(Ba, Bb, WT_DECW + 2*16384, B_DECB + 128, true);
    LAYER(Bb, Ba, WT_DECW + 3*16384, B_DECB + 256, true);
    LAYER(Ba, Bb, WT_DECWOUT,        B_DECB + 384, true);
    mmF(sm, cur, rg, Bb, acc, r15, hi);           // decWout
    __syncthreads();
    TRWRITE((float)pd[rt][nt][d], B_DECBO);
    __syncthreads();
    store_rows(sm, out1 + rowbase*128, 128, w, lane);
  } else {
    // ---- fet0 producer: enc + proj1 on t=0 rows ----
    size_t bbase = (size_t)(bid - 1632) * 64;
    loadW(Ba, wt + WT_ENCW, wbase, r15, hi);
#pragma unroll
    for (int i = 0; i < 2; ++i) {
      int idx = i*512 + tid, rl = idx >> 4, c = idx & 15;
      const float* s = x + (bbase + rl)*51*128 + c*8;
      f4 v0 = *(const f4*)s, v1 = *(const f4*)(s + 4);
      *(h8*)(sm + hoff(0, rl, c)) = cvt8(v0, v1);
    }
    bl[tid] = enc_b[tid];
    if (tid < 128) bl[1024 + tid] = enc_bout[tid];
    __syncthreads();
    int cur = 0;
    LAYER(Ba, Bb, WT_ENCW + 16384,   B_ENCB + 0,   true);
    LAYER(Bb, Ba, WT_ENCW + 2*16384, B_ENCB + 128, true);
    LAYER(Ba, Bb, WT_ENCW + 3*16384, B_ENCB + 256, true);
    LAYER(Bb, Ba, WT_ENCWOUT,        B_ENCB + 384, true);
    loadW(Bb, wt + WT_WENCI, 0, r15, hi);         // proj1 weights (cols 0..31)
    mmF(sm, cur, rg, Ba, acc, r15, hi);           // encWout
#pragma unroll
    for (int nt = 0; nt < 2; ++nt) {
      int n = wbase + nt*16 + r15; float bv = bl[B_ENCBO + n];
#pragma unroll
      for (int rt = 0; rt < 2; ++rt)
#pragma unroll
        for (int d = 0; d < 4; ++d) {
          int rl = rg*32 + rt*16 + hi*4 + d;
          float xv = x[(bbase + rl)*51*128 + n];
          float v = acc[rt][nt][d] + bv + xv;
          *(_Float16*)(sm + hoff(cur ^ 1, rl, n >> 3) + (n & 7)*2) = (_Float16)v;
        }
    }
    __syncthreads(); cur ^= 1;
    mmF(sm, cur, rg, Bb, acc, r15, hi);           // full_enc (cols 0..31, waves redundant/cg)
    if (cg == 0) {
#pragma unroll
      for (int nt = 0; nt < 2; ++nt) {
        int n = nt*16 + r15;
#pragma unroll
        for (int rt = 0; rt < 2; ++rt)
#pragma unroll
          for (int d = 0; d < 4; ++d) {
            int rl = rg*32 + rt*16 + hi*4 + d;
            fet0[(bbase + rl)*32 + n] = (_Float16)acc[rt][nt][d];
          }
      }
    }
  }
}

// ---------------- prediction kernel ----------------

__global__ __launch_bounds__(512, 4) void k_pred(
    const _Float16* __restrict__ fet0, const _Float16* __restrict__ wt,
    const _Float16* __restrict__ mst,
    const float* __restrict__ dec_b, const float* __restrict__ dec_bout,
    float* __restrict__ out3) {
  __shared__ char sm[LDS_BYTES];
  float* bl = (float*)(sm + 49152);
  int tid = threadIdx.x, w = tid >> 6, lane = tid & 63;
  int r15 = lane & 15, hi = lane >> 4;
  int rg = w >> 2, cg = w & 3, wbase = cg*32;
  int s = blockIdx.x >> 5, rb = blockIdx.x & 31;
  size_t bbase = (size_t)rb * 64;
  h8 Ba[8], Bb[8], Bm[2];
  f4 acc[2][2];

  loadW32(Bm, mst + (size_t)s*4096, wbase, r15, hi);
  loadW(Ba, wt + WT_DECW, wbase, r15, hi);
  if (tid < 256) {                                // stage fet0 -> h[0] chunks 0..3
    int rl = tid >> 2, c = tid & 3;
    *(h8*)(sm + hoff(0, rl, c)) = *(const h8*)(fet0 + (bbase + rl)*32 + c*8);
  }
  bl[tid] = dec_b[tid];
  if (tid < 128) bl[512 + tid] = dec_bout[tid];
  __syncthreads();

  // dec_in = cur @ Ms[s]  (K=32)
  mm32(sm, 0, rg, Bm, acc, r15, hi);
  h4 di[2][2];
#pragma unroll
  for (int rt = 0; rt < 2; ++rt)
#pragma unroll
    for (int nt = 0; nt < 2; ++nt)
#pragma unroll
      for (int d = 0; d < 4; ++d) di[rt][nt][d] = (_Float16)acc[rt][nt][d];
  hwrite(sm, 1, rg, wbase, acc, bl, -1, false, r15, hi);
  __syncthreads();
  int cur = 1;
  LAYER(Ba, Bb, WT_DECW + 16384,   0,   true);
  LAYER(Bb, Ba, WT_DECW + 2*16384, 128, true);
  LAYER(Ba, Bb, WT_DECW + 3*16384, 256, true);
  LAYER(Bb, Ba, WT_DECWOUT,        384, true);
  mmF(sm, cur, rg, Ba, acc, r15, hi);             // decWout
  __syncthreads();
  TRWRITE((float)di[rt][nt][d], 512);
  __syncthreads();
  store_rows(sm, out3 + (bbase*50 + s)*128, 50*128, w, lane);
}

// ---------------- launch ----------------

extern "C" void kernel_launch(void* const* d_in, const int* in_sizes, int n_in,
                              void* d_out, int out_size, void* d_ws, size_t ws_size,
                              hipStream_t stream) {
  const float* x        = (const float*)d_in[0];
  const float* encW     = (const float*)d_in[1];
  const float* enc_b    = (const float*)d_in[2];
  const float* encWout  = (const float*)d_in[3];
  const float* enc_bout = (const float*)d_in[4];
  const float* decW     = (const float*)d_in[5];
  const float* dec_b    = (const float*)d_in[6];
  const float* decWout  = (const float*)d_in[7];
  const float* dec_bout = (const float*)d_in[8];
  const float* wencI    = (const float*)d_in[9];
  const float* L        = (const float*)d_in[10];
  const float* wdecI    = (const float*)d_in[11];

  char* ws = (char*)d_ws;
  _Float16* wt   = (_Float16*)ws;
  _Float16* mst  = (_Float16*)(ws + MS_OFF_B);
  float*    ach  = (float*)(ws + ACH_OFF_B);
  _Float16* fet0 = (_Float16*)(ws + FET0_OFF_B);

  float* out1 = (float*)d_out;                       // autoencoder_output
  float* out2 = out1 + (size_t)ROWS_AUTO*128;        // outer_auto_output
  float* out3 = out2 + (size_t)ROWS_AUTO*128;        // predictions

  hipLaunchKernelGGL(k_prep, dim3(32, 12), dim3(512), 0, stream,
                     encW, encWout, decW, decWout, wencI, L, wt, ach);
  hipLaunchKernelGGL(k_aux, dim3(51), dim3(512), 0, stream,
                     ach, wencI, wdecI, mst, wt);
  hipLaunchKernelGGL(k_fused, dim3(1664), dim3(512), 0, stream,
                     x, wt, enc_b, enc_bout, dec_b, dec_bout, out1, out2, fet0);
  hipLaunchKernelGGL(k_pred, dim3(1600), dim3(512), 0, stream,
                     fet0, wt, mst, dec_b, dec_bout, out3);
}

// Round 4
// 244.009 us; speedup vs baseline: 1.8075x; 1.8075x over previous
//
#include <hip/hip_runtime.h>
#include <stdint.h>

// Koopman autoencoder — round 4 (MI355X / gfx950).
// Persistent per-stage weights in VGPRs (col-sliced per wave), h round-trips
// through LDS (1 barrier/layer, LDS-only drain), stage-split kernels,
// contiguous full-line output stores. f16 MFMA 16x16x32, fp32 accum.

typedef _Float16 h8 __attribute__((ext_vector_type(8)));
typedef float    f4 __attribute__((ext_vector_type(4)));

#define ROWS_AUTO 104448   // 2048*51
#define NTILE     3264     // 104448/32

// half-element offsets inside wt region of ws (all mats stored as W^T [n][k])
#define WT_ENCW      0
#define WT_ENCWOUT   (4*16384)
#define WT_DECW      (5*16384)
#define WT_DECWOUT   (9*16384)
#define WT_COMB      (10*16384)           // (WencI@WdecI)^T [128][128]

// ws byte offsets
#define MFULL_OFF_B 0x60000   // f16 [50][128][128]  (WencI@L^{s+1}@WdecI)^T
#define ACH_OFF_B   0x200000  // f32 [50][441]

// LDS per block: h0 [0,8K) h1 [8K,16K) peslot [16K,24K) trbuf [24K,40K) bl [40K,+2.5K)
#define LDS_BYTES 43520

__device__ __forceinline__ f4 mfma16(h8 a, h8 b, f4 c) {
  return __builtin_amdgcn_mfma_f32_16x16x32_f16(a, b, c, 0, 0, 0);
}
__device__ __forceinline__ h8 cvt8(f4 a, f4 b) {
  h8 r;
  r[0]=(_Float16)a[0]; r[1]=(_Float16)a[1]; r[2]=(_Float16)a[2]; r[3]=(_Float16)a[3];
  r[4]=(_Float16)b[0]; r[5]=(_Float16)b[1]; r[6]=(_Float16)b[2]; r[7]=(_Float16)b[3];
  return r;
}
// h/pe: row stride 256B, 16B chunks XOR-swizzled by row
__device__ __forceinline__ int hsw(int rl, int c) { return rl*256 + ((c ^ (rl & 7)) << 4); }
// trbuf: f32 rows 512B, 16B chunks swizzled
__device__ __forceinline__ int tsw(int r, int q) { return 24576 + r*512 + ((q ^ ((r & 7) << 2)) << 4); }

// wave's 32-col slice of a 128x128 W^T
__device__ __forceinline__ void loadW(h8 B[8], const _Float16* gW, int nbase, int r15, int hi) {
#pragma unroll
  for (int nt = 0; nt < 2; ++nt)
#pragma unroll
    for (int ks = 0; ks < 4; ++ks)
      B[nt*4+ks] = *(const h8*)(gW + (size_t)(nbase + nt*16 + r15)*128 + ks*32 + hi*8);
}

// [32 rows] x [128 k] @ regs-B -> acc[2][2] ; hb = byte offset of h buffer
__device__ __forceinline__ void mmF(const char* sm, int hb, const h8 B[8],
                                    f4 acc[2][2], int r15, int hi) {
#pragma unroll
  for (int rt = 0; rt < 2; ++rt)
#pragma unroll
    for (int nt = 0; nt < 2; ++nt) acc[rt][nt] = (f4){0.f,0.f,0.f,0.f};
#pragma unroll
  for (int ks = 0; ks < 4; ++ks) {
    int c = ks*4 + hi;
    h8 a0 = *(const h8*)(sm + hb + hsw(r15, c));
    h8 a1 = *(const h8*)(sm + hb + hsw(16 + r15, c));
    acc[0][0] = mfma16(a0, B[ks],   acc[0][0]);
    acc[0][1] = mfma16(a0, B[4+ks], acc[0][1]);
    acc[1][0] = mfma16(a1, B[ks],   acc[1][0]);
    acc[1][1] = mfma16(a1, B[4+ks], acc[1][1]);
  }
}

// ReLU(acc+b) -> h[hb] f16
__device__ __forceinline__ void hwrite(char* sm, int hb, int wbase, const f4 acc[2][2],
                                       const float* bl, int bo, int r15, int hi) {
#pragma unroll
  for (int nt = 0; nt < 2; ++nt) {
    int n = wbase + nt*16 + r15;
    float bv = bl[bo + n];
#pragma unroll
    for (int rt = 0; rt < 2; ++rt)
#pragma unroll
      for (int d = 0; d < 4; ++d) {
        int r = rt*16 + hi*4 + d;
        float v = fmaxf(acc[rt][nt][d] + bv, 0.f);
        *(_Float16*)(sm + hb + hsw(r, n >> 3) + (n & 7)*2) = (_Float16)v;
      }
  }
}

// trbuf -> global, contiguous: per instr 64 lanes cover 8 rows x 128B contiguous
template<bool NT>
__device__ __forceinline__ void store_rows(const char* sm, float* gbase, int rstride, int tid) {
  int rr = tid >> 3, qb = tid & 7;
#pragma unroll
  for (int i = 0; i < 4; ++i) {
    int q = i*8 + qb;
    f4 v = *(const f4*)(sm + tsw(rr, q));
    if (NT) __builtin_nontemporal_store(v, (f4*)(gbase + (size_t)rr*rstride + q*4));
    else    *(f4*)(gbase + (size_t)rr*rstride + q*4) = v;
  }
}

#define LAYER(BW, BO) do {                                   \
    mmF(sm, cur*8192, BW, acc, r15, hi);                     \
    hwrite(sm, (cur^1)*8192, wbase, acc, bl, BO, r15, hi);   \
    __syncthreads(); cur ^= 1;                               \
  } while (0)

// ---------------- prep kernels ----------------

__global__ __launch_bounds__(512) void k_prep(
    const float* __restrict__ encW, const float* __restrict__ encWout,
    const float* __restrict__ decW, const float* __restrict__ decWout,
    const float* __restrict__ L,
    _Float16* __restrict__ wt, float* __restrict__ ach) {
  __shared__ float chA[441], chB[441];
  int m = blockIdx.y, tid = threadIdx.x;
  if (m == 10) {                                  // serial L-power chain
    if (blockIdx.x != 0) return;
    if (tid < 441) chA[tid] = L[tid];
    __syncthreads();
    for (int s = 0; s < 50; ++s) {
      if (tid < 441) ach[s*441 + tid] = chA[tid];
      if (s == 49) break;
      if (tid < 441) {
        int i = tid / 21, j = tid % 21; float a = 0.f;
        for (int k = 0; k < 21; ++k) a += chA[i*21 + k] * L[k*21 + j];
        chB[tid] = a;
      }
      __syncthreads();
      if (tid < 441) chA[tid] = chB[tid];
      __syncthreads();
    }
    return;
  }
  int idx = blockIdx.x*512 + tid;
  if (idx >= 16384) return;
  const float* src; _Float16* dst;
  if (m < 4)       { src = encW + m*16384;     dst = wt + WT_ENCW + m*16384; }
  else if (m == 4) { src = encWout;            dst = wt + WT_ENCWOUT; }
  else if (m < 9)  { src = decW + (m-5)*16384; dst = wt + WT_DECW + (m-5)*16384; }
  else             { src = decWout;            dst = wt + WT_DECWOUT; }
  int n = idx >> 7, k = idx & 127;
  dst[idx] = (_Float16)src[k*128 + n];            // W^T[n][k]
}

// block s in [0,50]: s<50 -> Mfull_s = WencI @ L^{s+1} @ WdecI ; s==50 -> Wcomb
__global__ __launch_bounds__(512) void k_aux(
    const float* __restrict__ ach, const float* __restrict__ wencI,
    const float* __restrict__ wdecI,
    _Float16* __restrict__ mfull, _Float16* __restrict__ wt) {
  __shared__ float T1[2688];                      // [128 k][21 j]
  __shared__ float sa[441];
  int s = blockIdx.x, t = threadIdx.x;
  if (s < 50) {
    if (t < 441) sa[t] = ach[s*441 + t];
    __syncthreads();
    for (int idx = t; idx < 2688; idx += 512) {
      int k = idx / 21, j = idx % 21;
      float a = 0.f;
      for (int u = 0; u < 21; ++u) a += wencI[k*21 + u] * sa[u*21 + j];
      T1[idx] = a;
    }
  } else {
    for (int idx = t; idx < 2688; idx += 512) T1[idx] = wencI[idx];
  }
  __syncthreads();
  _Float16* dst = (s < 50) ? (mfull + (size_t)s*16384) : (wt + WT_COMB);
  for (int idx = t; idx < 16384; idx += 512) {    // M^T[n][k]
    int n = idx >> 7, k = idx & 127;
    float a = 0.f;
    for (int j = 0; j < 21; ++j) a += T1[k*21 + j] * wdecI[j*128 + n];
    dst[idx] = (_Float16)a;
  }
}

// ---------------- encoder kernel: x -> pe(out2), pd(out1) ----------------

__global__ __launch_bounds__(256, 2) void k_enc(
    const float* __restrict__ x, const _Float16* __restrict__ wt,
    const float* __restrict__ enc_b, const float* __restrict__ enc_bout,
    float* __restrict__ out1, float* __restrict__ out2) {
  __shared__ char sm[LDS_BYTES];
  float* bl = (float*)(sm + 40960);
  int tid = threadIdx.x, lane = tid & 63;
  int r15 = lane & 15, hi = lane >> 4;
  int wbase = (tid >> 6) * 32;
  h8 B0[8], B1[8], B2[8], B3[8], B4[8], B5[8];
  loadW(B0, wt + WT_ENCW,           wbase, r15, hi);
  loadW(B1, wt + WT_ENCW + 16384,   wbase, r15, hi);
  loadW(B2, wt + WT_ENCW + 2*16384, wbase, r15, hi);
  loadW(B3, wt + WT_ENCW + 3*16384, wbase, r15, hi);
  loadW(B4, wt + WT_ENCWOUT,        wbase, r15, hi);
  loadW(B5, wt + WT_COMB,           wbase, r15, hi);
  bl[tid] = enc_b[tid]; bl[256 + tid] = enc_b[256 + tid];
  if (tid < 128) bl[512 + tid] = enc_bout[tid];
  f4 acc[2][2];

  for (int t = blockIdx.x; t < NTILE; t += gridDim.x) {
    size_t rowbase = (size_t)t * 32;
    // stage x -> h0 + peslot (f16)
#pragma unroll
    for (int i = 0; i < 2; ++i) {
      int idx = i*256 + tid, rl = idx >> 4, c = idx & 15;
      const float* s = x + (rowbase + rl)*128 + c*8;
      f4 v0 = *(const f4*)s, v1 = *(const f4*)(s + 4);
      h8 hv = cvt8(v0, v1);
      int off = hsw(rl, c);
      *(h8*)(sm + off) = hv;
      *(h8*)(sm + 16384 + off) = hv;
    }
    __syncthreads();
    int cur = 0;
    LAYER(B0, 0); LAYER(B1, 128); LAYER(B2, 256); LAYER(B3, 384);
    mmF(sm, cur*8192, B4, acc, r15, hi);          // encWout
    // pe = acc + bout + x ; -> trbuf f32 and h[cur^1] f16
#pragma unroll
    for (int nt = 0; nt < 2; ++nt) {
      int n = wbase + nt*16 + r15;
      float bv = bl[512 + n];
#pragma unroll
      for (int rt = 0; rt < 2; ++rt)
#pragma unroll
        for (int d = 0; d < 4; ++d) {
          int r = rt*16 + hi*4 + d;
          float sk = (float)*(const _Float16*)(sm + 16384 + hsw(r, n >> 3) + (n & 7)*2);
          float v = acc[rt][nt][d] + bv + sk;
          *(_Float16*)(sm + (cur^1)*8192 + hsw(r, n >> 3) + (n & 7)*2) = (_Float16)v;
          *(float*)(sm + tsw(r, n >> 2) + (n & 3)*4) = v;
        }
    }
    __syncthreads();
    store_rows<false>(sm, out2 + rowbase*128, 128, tid);   // pe (cacheable)
    cur ^= 1;
    mmF(sm, cur*8192, B5, acc, r15, hi);          // pd = pe @ Wcomb
    __syncthreads();                              // trbuf reads done
#pragma unroll
    for (int nt = 0; nt < 2; ++nt) {
      int n = wbase + nt*16 + r15;
#pragma unroll
      for (int rt = 0; rt < 2; ++rt)
#pragma unroll
        for (int d = 0; d < 4; ++d) {
          int r = rt*16 + hi*4 + d;
          *(float*)(sm + tsw(r, n >> 2) + (n & 3)*4) = acc[rt][nt][d];
        }
    }
    __syncthreads();
    store_rows<false>(sm, out1 + rowbase*128, 128, tid);   // pd (cacheable)
    __syncthreads();
  }
}

// ---------------- decoder kernel: in-place dec res_block on out2 / out1 ----------------

__global__ __launch_bounds__(256, 2) void k_dec(
    const _Float16* __restrict__ wt,
    const float* __restrict__ dec_b, const float* __restrict__ dec_bout,
    float* __restrict__ out1, float* __restrict__ out2) {
  __shared__ char sm[LDS_BYTES];
  float* bl = (float*)(sm + 40960);
  int tid = threadIdx.x, lane = tid & 63;
  int r15 = lane & 15, hi = lane >> 4;
  int wbase = (tid >> 6) * 32;
  h8 B0[8], B1[8], B2[8], B3[8], B4[8];
  loadW(B0, wt + WT_DECW,           wbase, r15, hi);
  loadW(B1, wt + WT_DECW + 16384,   wbase, r15, hi);
  loadW(B2, wt + WT_DECW + 2*16384, wbase, r15, hi);
  loadW(B3, wt + WT_DECW + 3*16384, wbase, r15, hi);
  loadW(B4, wt + WT_DECWOUT,        wbase, r15, hi);
  bl[tid] = dec_b[tid]; bl[256 + tid] = dec_b[256 + tid];
  if (tid < 128) bl[512 + tid] = dec_bout[tid];
  f4 acc[2][2];

  for (int t = blockIdx.x; t < 2*NTILE; t += gridDim.x) {
    int rt0 = (t >= NTILE) ? t - NTILE : t;
    float* io = (t >= NTILE) ? out1 : out2;       // stream A: pd->out1, B: pe->out2
    float* p = io + (size_t)rt0 * 32 * 128;
#pragma unroll
    for (int i = 0; i < 2; ++i) {                 // stage input -> h0 + peslot
      int idx = i*256 + tid, rl = idx >> 4, c = idx & 15;
      const float* s = p + rl*128 + c*8;
      f4 v0 = *(const f4*)s, v1 = *(const f4*)(s + 4);
      h8 hv = cvt8(v0, v1);
      int off = hsw(rl, c);
      *(h8*)(sm + off) = hv;
      *(h8*)(sm + 16384 + off) = hv;
    }
    __syncthreads();
    int cur = 0;
    LAYER(B0, 0); LAYER(B1, 128); LAYER(B2, 256); LAYER(B3, 384);
    mmF(sm, cur*8192, B4, acc, r15, hi);          // decWout
#pragma unroll
    for (int nt = 0; nt < 2; ++nt) {
      int n = wbase + nt*16 + r15;
      float bv = bl[512 + n];
#pragma unroll
      for (int rt = 0; rt < 2; ++rt)
#pragma unroll
        for (int d = 0; d < 4; ++d) {
          int r = rt*16 + hi*4 + d;
          float sk = (float)*(const _Float16*)(sm + 16384 + hsw(r, n >> 3) + (n & 7)*2);
          float v = acc[rt][nt][d] + bv + sk;
          *(float*)(sm + tsw(r, n >> 2) + (n & 3)*4) = v;
        }
    }
    __syncthreads();
    store_rows<true>(sm, p, 128, tid);            // final, NT
    __syncthreads();
  }
}

// ---------------- prediction kernel: pe(t=0) @ Mfull_s -> dec -> out3 ----------------

__global__ __launch_bounds__(256, 2) void k_pred(
    const float* __restrict__ pe_src, const _Float16* __restrict__ wt,
    const _Float16* __restrict__ mfull,
    const float* __restrict__ dec_b, const float* __restrict__ dec_bout,
    float* __restrict__ out3) {
  __shared__ char sm[LDS_BYTES];
  float* bl = (float*)(sm + 40960);
  int tid = threadIdx.x, lane = tid & 63;
  int r15 = lane & 15, hi = lane >> 4;
  int wbase = (tid >> 6) * 32;
  h8 B0[8], B1[8], B2[8], B3[8], B4[8];
  loadW(B0, wt + WT_DECW,           wbase, r15, hi);
  loadW(B1, wt + WT_DECW + 16384,   wbase, r15, hi);
  loadW(B2, wt + WT_DECW + 2*16384, wbase, r15, hi);
  loadW(B3, wt + WT_DECW + 3*16384, wbase, r15, hi);
  loadW(B4, wt + WT_DECWOUT,        wbase, r15, hi);
  bl[tid] = dec_b[tid]; bl[256 + tid] = dec_b[256 + tid];
  if (tid < 128) bl[512 + tid] = dec_bout[tid];
  f4 acc[2][2];

  for (int u = blockIdx.x; u < 50*64; u += gridDim.x) {
    int s = u >> 6, rtile = u & 63;
    size_t bbase = (size_t)rtile * 32;
    h8 Bm[8];
    loadW(Bm, mfull + (size_t)s*16384, wbase, r15, hi);
#pragma unroll
    for (int i = 0; i < 2; ++i) {                 // stage pe t=0 rows -> h0
      int idx = i*256 + tid, rl = idx >> 4, c = idx & 15;
      const float* src = pe_src + (bbase + rl)*51*128 + c*8;
      f4 v0 = *(const f4*)src, v1 = *(const f4*)(src + 4);
      *(h8*)(sm + hsw(rl, c)) = cvt8(v0, v1);
    }
    __syncthreads();
    mmF(sm, 0, Bm, acc, r15, hi);                 // di = pe @ Mfull_s
#pragma unroll
    for (int nt = 0; nt < 2; ++nt) {
      int n = wbase + nt*16 + r15;
#pragma unroll
      for (int rt = 0; rt < 2; ++rt)
#pragma unroll
        for (int d = 0; d < 4; ++d) {
          int r = rt*16 + hi*4 + d;
          _Float16 hv = (_Float16)acc[rt][nt][d];
          *(_Float16*)(sm + 8192 + hsw(r, n >> 3) + (n & 7)*2) = hv;
          *(_Float16*)(sm + 16384 + hsw(r, n >> 3) + (n & 7)*2) = hv;
        }
    }
    __syncthreads();
    int cur = 1;
    LAYER(B0, 0); LAYER(B1, 128); LAYER(B2, 256); LAYER(B3, 384);
    mmF(sm, cur*8192, B4, acc, r15, hi);          // decWout (cur==1)
#pragma unroll
    for (int nt = 0; nt < 2; ++nt) {
      int n = wbase + nt*16 + r15;
      float bv = bl[512 + n];
#pragma unroll
      for (int rt = 0; rt < 2; ++rt)
#pragma unroll
        for (int d = 0; d < 4; ++d) {
          int r = rt*16 + hi*4 + d;
          float sk = (float)*(const _Float16*)(sm + 16384 + hsw(r, n >> 3) + (n & 7)*2);
          float v = acc[rt][nt][d] + bv + sk;
          *(float*)(sm + tsw(r, n >> 2) + (n & 3)*4) = v;
        }
    }
    __syncthreads();
    store_rows<true>(sm, out3 + (bbase*50 + s)*128, 50*128, tid);  // NT
    __syncthreads();
  }
}

// ---------------- launch ----------------

extern "C" void kernel_launch(void* const* d_in, const int* in_sizes, int n_in,
                              void* d_out, int out_size, void* d_ws, size_t ws_size,
                              hipStream_t stream) {
  const float* x        = (const float*)d_in[0];
  const float* encW     = (const float*)d_in[1];
  const float* enc_b    = (const float*)d_in[2];
  const float* encWout  = (const float*)d_in[3];
  const float* enc_bout = (const float*)d_in[4];
  const float* decW     = (const float*)d_in[5];
  const float* dec_b    = (const float*)d_in[6];
  const float* decWout  = (const float*)d_in[7];
  const float* dec_bout = (const float*)d_in[8];
  const float* wencI    = (const float*)d_in[9];
  const float* L        = (const float*)d_in[10];
  const float* wdecI    = (const float*)d_in[11];

  char* ws = (char*)d_ws;
  _Float16* wt    = (_Float16*)ws;
  _Float16* mfull = (_Float16*)(ws + MFULL_OFF_B);
  float*    ach   = (float*)(ws + ACH_OFF_B);

  float* out1 = (float*)d_out;                       // autoencoder_output
  float* out2 = out1 + (size_t)ROWS_AUTO*128;        // outer_auto_output
  float* out3 = out2 + (size_t)ROWS_AUTO*128;        // predictions [2048][50][128]

  hipLaunchKernelGGL(k_prep, dim3(32, 11), dim3(512), 0, stream,
                     encW, encWout, decW, decWout, L, wt, ach);
  hipLaunchKernelGGL(k_aux, dim3(51), dim3(512), 0, stream,
                     ach, wencI, wdecI, mfull, wt);
  hipLaunchKernelGGL(k_enc, dim3(512), dim3(256), 0, stream,
                     x, wt, enc_b, enc_bout, out1, out2);
  hipLaunchKernelGGL(k_pred, dim3(512), dim3(256), 0, stream,
                     out2, wt, mfull, dec_b, dec_bout, out3);
  hipLaunchKernelGGL(k_dec, dim3(512), dim3(256), 0, stream,
                     wt, dec_b, dec_bout, out1, out2);
}